// Round 3
// baseline (29619.568 us; speedup 1.0000x reference)
//
#include <hip/hip_runtime.h>
#include <hip/hip_cooperative_groups.h>

namespace cg = cooperative_groups;

typedef unsigned short u16;
typedef unsigned int   u32;
typedef _Float16 f16;
typedef f16   f16x2 __attribute__((ext_vector_type(2)));
typedef f16   f16x8 __attribute__((ext_vector_type(8)));
typedef float f32x4 __attribute__((ext_vector_type(4)));

#define B_  64
#define L_  384
#define CS  512   // SRC_DIM
#define H_  512
#define E_  256
#define NC  250
#define T_  127
#define XR  1280   // X row: [ctx 512 | emb 256 | h 512] f16

__device__ __forceinline__ float h2f(u16 u){ f16 h; __builtin_memcpy(&h,&u,2); return (float)h; }
__device__ __forceinline__ u16  f2h(float f){ f16 h=(f16)f; u16 u; __builtin_memcpy(&u,&h,2); return u; }
__device__ __forceinline__ float wredsum(float v){
#pragma unroll
  for (int o=32;o>0;o>>=1) v += __shfl_down(v, o, 64);
  return v;
}
__device__ __forceinline__ float tanh_f(float x){
  x = fminf(fmaxf(x, -15.f), 15.f);
  float e = __expf(2.f*x);
  return (e-1.f)/(e+1.f);
}
__device__ __forceinline__ float sigm_f(float x){
  x = fminf(fmaxf(x, -30.f), 30.f);
  return 1.f/(1.f+__expf(-x));
}
__device__ __forceinline__ float dot2f(u32 a, u32 b, float c){
  f16x2 x, y; __builtin_memcpy(&x,&a,4); __builtin_memcpy(&y,&b,4);
#if __has_builtin(__builtin_amdgcn_fdot2)
  return __builtin_amdgcn_fdot2(x, y, c, false);
#else
  return c + (float)x[0]*(float)y[0] + (float)x[1]*(float)y[1];
#endif
}

// ---------------- one-time converters ----------------
__global__ __launch_bounds__(256) void k_cvt(const float* __restrict__ in, f16* __restrict__ o, int n){
  int i = blockIdx.x*256 + threadIdx.x;
  if (i < n) o[i] = (f16)in[i];
}

// k-pair-packed Wh2h: WhPk[kp*512 + n] = (Wh2h[n][2kp], Wh2h[n][2kp+1]) as f16x2 in u32
__global__ __launch_bounds__(256) void k_packwhp(const float* __restrict__ Wh, u32* __restrict__ Wp){
  int i = blockIdx.x*256 + threadIdx.x;   // over 256*512
  if (i < 256*512){
    int kp = i >> 9, n = i & 511;
    u32 lo = f2h(Wh[(size_t)n*512 + 2*kp]);
    u32 hi = f2h(Wh[(size_t)n*512 + 2*kp+1]);
    Wp[i] = lo | (hi<<16);
  }
}

// MFMA-fragment-packed gates weights.
// Packed gate-row p = j*16 + l16, l16 = g*4+hl  <->  orig row r = g*512 + j*4 + hl.
// WgP flat: (((j*10 + kc)*4 + kk)*64 + lane)*8 + e ; lane=(quad,l16); k = kc*128+kk*32+quad*8+e
// k<768 -> W_ih[r][k] ([ctx|emb]); k>=768 -> W_hh[r][k-768].
__global__ __launch_bounds__(256) void k_packwgp(const float* __restrict__ Wih,
    const float* __restrict__ Whh, const float* __restrict__ bih, const float* __restrict__ bhh,
    f16* __restrict__ WgP, float* __restrict__ bias_g){
  int i = blockIdx.x*256 + threadIdx.x;   // over 128*20480
  if (i < 128*20480){
    int j = i / 20480, rem = i % 20480;
    int kc = rem >> 11, kk = (rem>>9)&3, lane = (rem>>3)&63, e = rem&7;
    int quad = lane>>4, l16 = lane&15;
    int g = l16>>2, hl = l16&3;
    int r = g*512 + j*4 + hl;
    int k = kc*128 + kk*32 + quad*8 + e;
    float v = (k<768) ? Wih[(size_t)r*768 + k] : Whh[(size_t)r*512 + (k-768)];
    WgP[i] = (f16)v;
    if (kc==0 && kk==0 && quad==0 && e==0)
      bias_g[j*16 + l16] = bih[r] + bhh[r];
  }
}

// Precompute all step embeddings: embseq[(b*T + t)*256 + col] (f16)
__global__ __launch_bounds__(256) void k_emb(const int* __restrict__ text,
    const float* __restrict__ embt, f16* __restrict__ embseq){
  int i = blockIdx.x*256 + threadIdx.x;
  if (i < B_*T_*E_){
    int bt = i >> 8, col = i & 255;
    int tok = text[bt];
    embseq[i] = (f16)embt[(size_t)tok*E_ + col];
  }
}

// ---------------- GEMM1 (MFMA): sf = src(f32) @ Wi2h16^T -> f16. M=24576, N=512, K=512
__global__ __launch_bounds__(256) void k_sf_mfma(
    const float* __restrict__ A, const f16* __restrict__ Wn, u16* __restrict__ sf)
{
  int w = threadIdx.x >> 6, lane = threadIdx.x & 63;
  int quad = lane >> 4, l16 = lane & 15;
  int m0 = blockIdx.x * 64;
  int nb = blockIdx.y * 256 + w * 64;
  const float* ap0 = A  + (size_t)(m0 + l16)*512 + quad*8;
  const f16*   bp0 = Wn + (size_t)(nb + l16)*512 + quad*8;
  f32x4 acc[4][4] = {};
  for (int k0=0; k0<512; k0+=32){
    f16x8 bfr[4];
#pragma unroll
    for (int nt=0; nt<4; nt++)
      bfr[nt] = *(const f16x8*)(bp0 + (size_t)nt*16*512 + k0);
#pragma unroll
    for (int f=0; f<4; f++){
      const float* ap = ap0 + (size_t)f*16*512 + k0;
      float4 a0 = *(const float4*)ap;
      float4 a1 = *(const float4*)(ap+4);
      f16x8 afr = { (f16)a0.x,(f16)a0.y,(f16)a0.z,(f16)a0.w,
                    (f16)a1.x,(f16)a1.y,(f16)a1.z,(f16)a1.w };
#pragma unroll
      for (int nt=0; nt<4; nt++)
        acc[f][nt] = __builtin_amdgcn_mfma_f32_16x16x32_f16(afr, bfr[nt], acc[f][nt], 0,0,0);
    }
  }
#pragma unroll
  for (int f=0; f<4; f++)
#pragma unroll
    for (int nt=0; nt<4; nt++)
#pragma unroll
      for (int r=0; r<4; r++){
        int m = m0 + f*16 + quad*4 + r;
        int n = nb + nt*16 + l16;
        sf[(size_t)m*512 + n] = f2h(acc[f][nt][r]);
      }
}

// ---------------- GEMM2: probs = hs @ Wgen^T + bgen
__global__ __launch_bounds__(256) void gemm_probs(
    const u16* __restrict__ A, const float* __restrict__ W, const float* __restrict__ bias,
    float* __restrict__ Cd, int M, int N, int K)
{
  __shared__ float As[16][64+1];
  __shared__ float Ws[16][64+1];
  const int tid = threadIdx.x;
  const int bm = blockIdx.x*64, bn = blockIdx.y*64;
  const int lr = tid>>2;
  const int lc = (tid&3)*4;
  const int ty = tid>>4, tx = tid&15;
  float acc[4][4];
#pragma unroll
  for (int i=0;i<4;i++)
#pragma unroll
    for (int j=0;j<4;j++) acc[i][j]=0.f;

  for (int k0=0;k0<K;k0+=16){
    ushort4 va = *(const ushort4*)(A + (size_t)(bm+lr)*K + k0 + lc);
    As[lc+0][lr]=h2f(va.x); As[lc+1][lr]=h2f(va.y); As[lc+2][lr]=h2f(va.z); As[lc+3][lr]=h2f(va.w);
    int n = bn + lr;
    if (n < N){
      float4 vw = *(const float4*)(W + (size_t)n*K + k0 + lc);
      Ws[lc+0][lr]=vw.x; Ws[lc+1][lr]=vw.y; Ws[lc+2][lr]=vw.z; Ws[lc+3][lr]=vw.w;
    } else {
      Ws[lc+0][lr]=0.f; Ws[lc+1][lr]=0.f; Ws[lc+2][lr]=0.f; Ws[lc+3][lr]=0.f;
    }
    __syncthreads();
#pragma unroll
    for (int k=0;k<16;k++){
      float a[4], w[4];
#pragma unroll
      for (int i=0;i<4;i++) a[i]=As[k][ty*4+i];
#pragma unroll
      for (int j=0;j<4;j++) w[j]=Ws[k][tx*4+j];
#pragma unroll
      for (int i=0;i<4;i++)
#pragma unroll
        for (int j=0;j<4;j++) acc[i][j] += a[i]*w[j];
    }
    __syncthreads();
  }
#pragma unroll
  for (int i=0;i<4;i++){
    int m = bm + ty*4 + i;
#pragma unroll
    for (int j=0;j<4;j++){
      int n = bn + tx*4 + j;
      if (n < N) Cd[(size_t)m*N + n] = acc[i][j] + bias[n];
    }
  }
}

// ---------------- persistent decode loop ----------------
// grid 256 x 512. Block g -> (b = g>>2, s = g&3): n/c slice [128s, 128s+128).
// LDS-persistent: sf[b,:,slice] (96 KB). Reg-persistent: Wh2h[:, slice] k-pair packed (64 u32/thr).
// Per step: P1 proj(reg-dot2)+logit-partial -> gsync -> P2 softmax+ctx+emb -> gsync ->
//           P3 (blocks 0..127) gates MFMA (X LDS-staged, WgP frag-packed) + cell -> gsync.
__global__ __launch_bounds__(512,1) void k_loop(
    const u16* __restrict__ sfw, const f16* __restrict__ src16,
    const u32* __restrict__ WhPk, const float* __restrict__ bh2h,
    const float* __restrict__ wsc,
    const f16* __restrict__ WgP, const float* __restrict__ bias_g,
    const f16* __restrict__ embseq,
    f16* __restrict__ X0, f16* __restrict__ X1,
    float* __restrict__ pl, float* __restrict__ cbuf,
    u16* __restrict__ hs)
{
  cg::grid_group grid = cg::this_grid();
  const int tid  = threadIdx.x;
  const int wid  = tid >> 6;
  const int lane = tid & 63;
  const int b = blockIdx.x >> 2;
  const int s = blockIdx.x & 3;

  __shared__ u32   sh_sf[L_*64];        // 96 KB: [l*64 + lane] = sf f16-pair
  __shared__ float sh_pp[8][130];
  __shared__ float sh_proj[128];
  __shared__ u32   sh_h2[256];
  __shared__ float sh_logit[L_];
  __shared__ float sh_al[L_];
  __shared__ float sh_red[16];
  __shared__ f16   sh_x[64][144];       // 18 KB X staging (P3)
  __shared__ float sh_g[2][64][17];
  __shared__ float sh_cp[8][130];

  // ---- persistent Wh2h slice in registers (k-pair packed) ----
  u32 wr0[32], wr1[32];
  const int n0 = s*128 + lane*2;
#pragma unroll
  for (int jj=0;jj<32;jj++){
    wr0[jj] = WhPk[(size_t)(wid*32+jj)*512 + n0];
    wr1[jj] = WhPk[(size_t)(wid*32+jj)*512 + n0 + 1];
  }
  const float wv0 = wsc[n0], wv1 = wsc[n0+1];

  // ---- persistent sf slice in LDS ----
  {
    const u32* sp = (const u32*)sfw + ((size_t)b*L_)*256 + s*64 + lane;
#pragma unroll 4
    for (int i=0;i<48;i++){
      int l = wid*48 + i;
      sh_sf[l*64 + lane] = sp[(size_t)l*256];
    }
  }
  __syncthreads();

  for (int t=0; t<T_; ++t){
    f16* Xc = (t & 1) ? X1 : X0;
    f16* Xn = (t & 1) ? X0 : X1;

    // ================= P1: proj (registers) + logit n-partial =================
    if (tid < 256) sh_h2[tid] = ((const u32*)(Xc + (size_t)b*XR + 768))[tid];
    __syncthreads();
    {
      float a0=0.f, a1=0.f;
#pragma unroll
      for (int jj=0;jj<32;jj++){
        u32 hv = sh_h2[wid*32 + jj];
        a0 = dot2f(wr0[jj], hv, a0);
        a1 = dot2f(wr1[jj], hv, a1);
      }
      sh_pp[wid][lane*2  ] = a0;
      sh_pp[wid][lane*2+1] = a1;
    }
    __syncthreads();
    if (tid < 128){
      float v = ((sh_pp[0][tid]+sh_pp[1][tid])+(sh_pp[2][tid]+sh_pp[3][tid]))
              + ((sh_pp[4][tid]+sh_pp[5][tid])+(sh_pp[6][tid]+sh_pp[7][tid]))
              + bh2h[s*128 + tid];
      sh_proj[tid] = v;
    }
    __syncthreads();
    {
      const float pv0 = sh_proj[lane*2], pv1 = sh_proj[lane*2+1];
      float* plp = pl + ((size_t)(b*4 + s))*L_;
#pragma unroll 4
      for (int i=0;i<48;i++){
        int l = wid*48 + i;
        u32 sv = sh_sf[l*64 + lane];
        f16x2 sp2; __builtin_memcpy(&sp2,&sv,4);
        float v = tanh_f((float)sp2[0] + pv0)*wv0
                + tanh_f((float)sp2[1] + pv1)*wv1;
        v = wredsum(v);
        if (lane==0) plp[l] = v;
      }
    }
    __threadfence();
    grid.sync();

    // ================= P2: softmax + context slice + emb copy =================
    if (tid < L_){
      const float* q = pl + (size_t)b*4*L_ + tid;
      sh_logit[tid] = (q[0]+q[L_]) + (q[2*L_]+q[3*L_]);
    }
    __syncthreads();
    float inv;
    {
      float va = (tid < L_) ? sh_logit[tid] : -3.0e38f;
      float m = va;
#pragma unroll
      for (int o=32;o>0;o>>=1) m = fmaxf(m, __shfl_down(m,o,64));
      if (lane==0) sh_red[wid] = m;
      __syncthreads();
      m = fmaxf(fmaxf(fmaxf(sh_red[0],sh_red[1]),fmaxf(sh_red[2],sh_red[3])),
                fmaxf(fmaxf(sh_red[4],sh_red[5]),fmaxf(sh_red[6],sh_red[7])));
      float e = (tid < L_) ? __expf(va - m) : 0.f;
      if (tid < L_) sh_al[tid] = e;
      float ss = wredsum(e);
      if (lane==0) sh_red[8+wid] = ss;
      __syncthreads();
      inv = 1.f/(((sh_red[8]+sh_red[9])+(sh_red[10]+sh_red[11]))
               + ((sh_red[12]+sh_red[13])+(sh_red[14]+sh_red[15])));
    }
    {
      const u32* srcp = (const u32*)src16 + ((size_t)b*L_)*256 + s*64 + lane;
      float c0=0.f, c1=0.f;
#pragma unroll 6
      for (int i=0;i<48;i++){
        int l = wid*48 + i;
        u32 v = srcp[(size_t)l*256];
        f16x2 p2; __builtin_memcpy(&p2,&v,4);
        float al = sh_al[l];
        c0 += al*(float)p2[0];
        c1 += al*(float)p2[1];
      }
      sh_cp[wid][lane*2  ] = c0;
      sh_cp[wid][lane*2+1] = c1;
    }
    if (s==0 && tid>=128 && tid<256){
      int c = tid-128;
      ((u32*)(Xc + (size_t)b*XR + 512))[c] =
          ((const u32*)(embseq + ((size_t)(b*T_ + t))*256))[c];
    }
    __syncthreads();
    if (tid < 64){
      float v0 = (((sh_cp[0][tid*2]+sh_cp[1][tid*2])+(sh_cp[2][tid*2]+sh_cp[3][tid*2]))
                + ((sh_cp[4][tid*2]+sh_cp[5][tid*2])+(sh_cp[6][tid*2]+sh_cp[7][tid*2])))*inv;
      float v1 = (((sh_cp[0][tid*2+1]+sh_cp[1][tid*2+1])+(sh_cp[2][tid*2+1]+sh_cp[3][tid*2+1]))
                + ((sh_cp[4][tid*2+1]+sh_cp[5][tid*2+1])+(sh_cp[6][tid*2+1]+sh_cp[7][tid*2+1])))*inv;
      u32 o = (u32)f2h(v0) | ((u32)f2h(v1)<<16);
      ((u32*)(Xc + (size_t)b*XR + s*128))[tid] = o;
    }
    __threadfence();
    grid.sync();

    // ================= P3: gates MFMA + LSTM cell (blocks 0..127) =================
    if (blockIdx.x < 128){
      const int j = blockIdx.x;
      const int quad = lane>>4, l16 = lane&15;
      const int bg = wid & 3, kh = wid >> 2;   // batch-group, k-half
      f32x4 acc = {};
      for (int kc=0; kc<10; ++kc){
#pragma unroll
        for (int h2v=0; h2v<2; h2v++){
          int row  = (tid>>4) + h2v*32;
          int cseg = (tid&15)*8;
          *(f16x8*)&sh_x[row][cseg] = *(const f16x8*)(Xc + (size_t)row*XR + kc*128 + cseg);
        }
        __syncthreads();
        if (kc >= kh*5 && kc < kh*5+5){
          const f16* wp = WgP + (size_t)(j*10 + kc)*2048 + lane*8;
#pragma unroll
          for (int kk=0; kk<4; kk++){
            f16x8 afr = *(const f16x8*)&sh_x[bg*16 + l16][kk*32 + quad*8];
            f16x8 bfr = *(const f16x8*)(wp + kk*512);
            acc = __builtin_amdgcn_mfma_f32_16x16x32_f16(afr, bfr, acc, 0,0,0);
          }
        }
        __syncthreads();
      }
#pragma unroll
      for (int r=0;r<4;r++) sh_g[kh][bg*16 + quad*4 + r][l16] = acc[r];
      __syncthreads();
      if (tid < 256){
        int b2 = tid>>2, hl = tid&3;
        float gi = sh_g[0][b2][ 0+hl] + sh_g[1][b2][ 0+hl] + bias_g[j*16 +  0 + hl];
        float gf = sh_g[0][b2][ 4+hl] + sh_g[1][b2][ 4+hl] + bias_g[j*16 +  4 + hl];
        float gg = sh_g[0][b2][ 8+hl] + sh_g[1][b2][ 8+hl] + bias_g[j*16 +  8 + hl];
        float go = sh_g[0][b2][12+hl] + sh_g[1][b2][12+hl] + bias_g[j*16 + 12 + hl];
        float fi=sigm_f(gi), ff=sigm_f(gf), fg=tanh_f(gg), fo=sigm_f(go);
        int hd = j*4 + hl;
        size_t ci = ((size_t)b2<<9) + hd;
        float cn = ff*cbuf[ci] + fi*fg;
        float hn = fo*tanh_f(cn);
        cbuf[ci] = cn;
        Xn[(size_t)b2*XR + 768 + hd] = (f16)hn;
        hs[((size_t)(b2*T_ + t))*512 + hd] = f2h(hn);
      }
    }
    __threadfence();
    grid.sync();
  }
}

extern "C" void kernel_launch(void* const* d_in, const int* in_sizes, int n_in,
                              void* d_out, int out_size, void* d_ws, size_t ws_size,
                              hipStream_t stream)
{
  const float* src   = (const float*)d_in[0];
  const int*   text  = (const int*)d_in[1];
  const float* embt  = (const float*)d_in[2];
  const float* Wi2h  = (const float*)d_in[3];
  const float* Wh2h  = (const float*)d_in[4];
  const float* bh2h  = (const float*)d_in[5];
  const float* wsc   = (const float*)d_in[6];
  const float* W_ih  = (const float*)d_in[7];
  const float* b_ih  = (const float*)d_in[8];
  const float* W_hh  = (const float*)d_in[9];
  const float* b_hh  = (const float*)d_in[10];
  const float* Wgen  = (const float*)d_in[11];
  const float* bgen  = (const float*)d_in[12];
  float* out = (float*)d_out;

  // Workspace (~71 MB)
  char* p = (char*)d_ws;
  u16*   sfw    = (u16*)p;    p += (size_t)B_*L_*H_*2;        // 25.2 MB
  u16*   hsw    = (u16*)p;    p += (size_t)B_*T_*H_*2;        //  8.3 MB
  f16*   src16  = (f16*)p;    p += (size_t)B_*L_*CS*2;        // 25.2 MB
  u32*   WhPk   = (u32*)p;    p += (size_t)256*512*4;         //  0.5 MB
  f16*   Wi2h16 = (f16*)p;    p += (size_t)H_*CS*2;           //  0.5 MB
  f16*   WgP    = (f16*)p;    p += (size_t)128*20480*2;       //  5.2 MB
  f16*   embseq = (f16*)p;    p += (size_t)B_*T_*E_*2;        //  4.2 MB
  f16*   X0     = (f16*)p;    p += (size_t)B_*XR*2;           //  160 KB
  f16*   X1     = (f16*)p;    p += (size_t)B_*XR*2;           //  160 KB
  float* plb    = (float*)p;  p += (size_t)B_*4*L_*4;         //  393 KB
  float* cbuf   = (float*)p;  p += (size_t)B_*H_*4;           //  128 KB
  float* bias_g = (float*)p;  p += (size_t)2048*4;            //    8 KB

  hipMemsetAsync(X0,   0, (size_t)B_*XR*2*2, stream);   // X0+X1 contiguous
  hipMemsetAsync(cbuf, 0, (size_t)B_*H_*4, stream);

  // one-time conversions / packing
  k_cvt    <<<(H_*CS+255)/256,    256, 0, stream>>>(Wi2h, Wi2h16, H_*CS);
  k_cvt    <<<(B_*L_*CS+255)/256, 256, 0, stream>>>(src, src16, B_*L_*CS);
  k_packwhp<<<(256*512+255)/256,  256, 0, stream>>>(Wh2h, WhPk);
  k_packwgp<<<(128*20480+255)/256,256, 0, stream>>>(W_ih, W_hh, b_ih, b_hh, WgP, bias_g);
  k_emb    <<<(B_*T_*E_+255)/256, 256, 0, stream>>>(text, embt, embseq);

  // sf = src @ Wi2h^T  (MFMA f16)
  k_sf_mfma<<<dim3(384,2), 256, 0, stream>>>(src, Wi2h16, sfw);

  // persistent decode loop (cooperative): 256 blocks x 512 threads
  const u16* sf_a = sfw;
  const f16* src_a = src16;
  const u32* whp_a = WhPk;
  const f16* wgp_a = WgP;
  const f16* emb_a = embseq;
  void* ka[] = {
    (void*)&sf_a, (void*)&src_a, (void*)&whp_a, (void*)&bh2h, (void*)&wsc,
    (void*)&wgp_a, (void*)&bias_g, (void*)&emb_a,
    (void*)&X0, (void*)&X1, (void*)&plb, (void*)&cbuf, (void*)&hsw
  };
  hipLaunchCooperativeKernel(reinterpret_cast<void*>(k_loop),
                             dim3(256), dim3(512), ka, 0, stream);

  // probs = hs @ Wgen^T + bgen
  dim3 g2(B_*T_/64, (NC+63)/64);
  gemm_probs<<<g2, 256, 0, stream>>>(hsw, Wgen, bgen, out, B_*T_, NC, H_);
}

// Round 4
// 5016.113 us; speedup vs baseline: 5.9049x; 5.9049x over previous
//
#include <hip/hip_runtime.h>

typedef unsigned short u16;
typedef unsigned int   u32;
typedef _Float16 f16;
typedef f16   f16x2 __attribute__((ext_vector_type(2)));
typedef f16   f16x8 __attribute__((ext_vector_type(8)));
typedef float f32x4 __attribute__((ext_vector_type(4)));
typedef u32   u32x4 __attribute__((ext_vector_type(4)));

#define B_  64
#define L_  384
#define CS  512   // SRC_DIM
#define H_  512
#define E_  256
#define NC  250
#define T_  127
#define XROW 1024  // per-batch X row: [ctx(512) | h(512)] f16

__device__ __forceinline__ float h2f(u16 u){ f16 h; __builtin_memcpy(&h,&u,2); return (float)h; }
__device__ __forceinline__ u16  f2h(float f){ f16 h=(f16)f; u16 u; __builtin_memcpy(&u,&h,2); return u; }
__device__ __forceinline__ float wredsum(float v){
#pragma unroll
  for (int o=32;o>0;o>>=1) v += __shfl_down(v, o, 64);
  return v;
}
__device__ __forceinline__ float tanh_f(float x){
  x = fminf(fmaxf(x, -15.f), 15.f);
  float e = __expf(2.f*x);
  return (e-1.f)/(e+1.f);
}
__device__ __forceinline__ float sigm_f(float x){
  x = fminf(fmaxf(x, -30.f), 30.f);
  return 1.f/(1.f+__expf(-x));
}
__device__ __forceinline__ float dot2f(u32 a, u32 b, float c){
  f16x2 x, y; __builtin_memcpy(&x,&a,4); __builtin_memcpy(&y,&b,4);
#if __has_builtin(__builtin_amdgcn_fdot2)
  return __builtin_amdgcn_fdot2(x, y, c, false);
#else
  return c + (float)x[0]*(float)y[0] + (float)x[1]*(float)y[1];
#endif
}

// ---------------- one-time converters ----------------
__global__ __launch_bounds__(256) void k_cvt(const float* __restrict__ in, f16* __restrict__ o, int n){
  int i = blockIdx.x*256 + threadIdx.x;
  if (i < n) o[i] = (f16)in[i];
}

// Quad-k-pair-packed Wh2h for coalesced column-parallel proj:
// WhQ[((kq*512)+n)*4 + e] = (Wh2h[n][8kq+2e], Wh2h[n][8kq+2e+1]) as f16-pair u32.
// kq in [0,64), n in [0,512), e in [0,4). Thread owning col n loads u32x4 per kq.
__global__ __launch_bounds__(256) void k_packwhq(const float* __restrict__ Wh, u32* __restrict__ Wq){
  int i = blockIdx.x*256 + threadIdx.x;   // over 64*512*4
  if (i < 64*512*4){
    int kq = i >> 11, n = (i >> 2) & 511, e = i & 3;
    int k = kq*8 + e*2;
    u32 lo = f2h(Wh[(size_t)n*512 + k]);
    u32 hi = f2h(Wh[(size_t)n*512 + k + 1]);
    Wq[i] = lo | (hi<<16);
  }
}

// Permuted gates-weight pack (verified round 2). Packed row p = j*16 + g*4 + hl  <->
// orig row r = g*512 + j*4 + hl. cols: [0,768) = W_ih row r, [768,1280) = W_hh row r.
__global__ __launch_bounds__(256) void k_packwg(const float* __restrict__ Wih,
    const float* __restrict__ Whh, const float* __restrict__ bih, const float* __restrict__ bhh,
    f16* __restrict__ Wg, float* __restrict__ bias_g){
  int i = blockIdx.x*256 + threadIdx.x;   // over 2048*1280
  if (i < 2048*1280){
    int p = i / 1280, c = i - p*1280;
    int j = p >> 4, q = p & 15, g = q >> 2, hl = q & 3;
    int r = g*512 + (j<<2) + hl;
    float v = (c < 768) ? Wih[(size_t)r*768 + c] : Whh[(size_t)r*512 + (c-768)];
    Wg[i] = (f16)v;
    if (c == 0) bias_g[p] = bih[r] + bhh[r];
  }
}

// Precompute all step embeddings: embseq[(b*T + t)*256 + col] (f16)
__global__ __launch_bounds__(256) void k_emb(const int* __restrict__ text,
    const float* __restrict__ embt, f16* __restrict__ embseq){
  int i = blockIdx.x*256 + threadIdx.x;
  if (i < B_*T_*E_){
    int bt = i >> 8, col = i & 255;
    int tok = text[bt];
    embseq[i] = (f16)embt[(size_t)tok*E_ + col];
  }
}

// ---------------- GEMM1 (MFMA): sf = src(f32) @ Wi2h16^T -> f16 (verified)
__global__ __launch_bounds__(256) void k_sf_mfma(
    const float* __restrict__ A, const f16* __restrict__ Wn, u16* __restrict__ sf)
{
  int w = threadIdx.x >> 6, lane = threadIdx.x & 63;
  int quad = lane >> 4, l16 = lane & 15;
  int m0 = blockIdx.x * 64;
  int nb = blockIdx.y * 256 + w * 64;
  const float* ap0 = A  + (size_t)(m0 + l16)*512 + quad*8;
  const f16*   bp0 = Wn + (size_t)(nb + l16)*512 + quad*8;
  f32x4 acc[4][4] = {};
  for (int k0=0; k0<512; k0+=32){
    f16x8 bfr[4];
#pragma unroll
    for (int nt=0; nt<4; nt++)
      bfr[nt] = *(const f16x8*)(bp0 + (size_t)nt*16*512 + k0);
#pragma unroll
    for (int f=0; f<4; f++){
      const float* ap = ap0 + (size_t)f*16*512 + k0;
      float4 a0 = *(const float4*)ap;
      float4 a1 = *(const float4*)(ap+4);
      f16x8 afr = { (f16)a0.x,(f16)a0.y,(f16)a0.z,(f16)a0.w,
                    (f16)a1.x,(f16)a1.y,(f16)a1.z,(f16)a1.w };
#pragma unroll
      for (int nt=0; nt<4; nt++)
        acc[f][nt] = __builtin_amdgcn_mfma_f32_16x16x32_f16(afr, bfr[nt], acc[f][nt], 0,0,0);
    }
  }
#pragma unroll
  for (int f=0; f<4; f++)
#pragma unroll
    for (int nt=0; nt<4; nt++)
#pragma unroll
      for (int r=0; r<4; r++){
        int m = m0 + f*16 + quad*4 + r;
        int n = nb + nt*16 + l16;
        sf[(size_t)m*512 + n] = f2h(acc[f][nt][r]);
      }
}

// ---------------- GEMM2: probs = hs @ Wgen^T + bgen (verified)
__global__ __launch_bounds__(256) void gemm_probs(
    const u16* __restrict__ A, const float* __restrict__ W, const float* __restrict__ bias,
    float* __restrict__ Cd, int M, int N, int K)
{
  __shared__ float As[16][64+1];
  __shared__ float Ws[16][64+1];
  const int tid = threadIdx.x;
  const int bm = blockIdx.x*64, bn = blockIdx.y*64;
  const int lr = tid>>2;
  const int lc = (tid&3)*4;
  const int ty = tid>>4, tx = tid&15;
  float acc[4][4];
#pragma unroll
  for (int i=0;i<4;i++)
#pragma unroll
    for (int j=0;j<4;j++) acc[i][j]=0.f;

  for (int k0=0;k0<K;k0+=16){
    ushort4 va = *(const ushort4*)(A + (size_t)(bm+lr)*K + k0 + lc);
    As[lc+0][lr]=h2f(va.x); As[lc+1][lr]=h2f(va.y); As[lc+2][lr]=h2f(va.z); As[lc+3][lr]=h2f(va.w);
    int n = bn + lr;
    if (n < N){
      float4 vw = *(const float4*)(W + (size_t)n*K + k0 + lc);
      Ws[lc+0][lr]=vw.x; Ws[lc+1][lr]=vw.y; Ws[lc+2][lr]=vw.z; Ws[lc+3][lr]=vw.w;
    } else {
      Ws[lc+0][lr]=0.f; Ws[lc+1][lr]=0.f; Ws[lc+2][lr]=0.f; Ws[lc+3][lr]=0.f;
    }
    __syncthreads();
#pragma unroll
    for (int k=0;k<16;k++){
      float a[4], w[4];
#pragma unroll
      for (int i=0;i<4;i++) a[i]=As[k][ty*4+i];
#pragma unroll
      for (int j=0;j<4;j++) w[j]=Ws[k][tx*4+j];
#pragma unroll
      for (int i=0;i<4;i++)
#pragma unroll
        for (int j=0;j<4;j++) acc[i][j] += a[i]*w[j];
    }
    __syncthreads();
  }
#pragma unroll
  for (int i=0;i<4;i++){
    int m = bm + ty*4 + i;
#pragma unroll
    for (int j=0;j<4;j++){
      int n = bn + tx*4 + j;
      if (n < N) Cd[(size_t)m*N + n] = acc[i][j] + bias[n];
    }
  }
}

// ---------------- step kernel A: proj (redundant x4, coalesced) + logit slice.
// grid 256 (4 per batch) x 512 threads. Block (b = g>>2, q = g&3) covers l in [96q, 96q+96).
__global__ __launch_bounds__(512) void k_att1(
    const u32* __restrict__ WhQ, const u16* __restrict__ sf,
    const f16* __restrict__ Xc, const float* __restrict__ bh2h,
    const float* __restrict__ wsc, float* __restrict__ logit)
{
  const int b   = blockIdx.x >> 2;
  const int q   = blockIdx.x & 3;
  const int tid = threadIdx.x;
  const int wid = tid >> 6, lane = tid & 63;

  __shared__ __align__(16) u32 sh_h2[256];   // h (512 f16) as pairs
  __shared__ float sh_proj[512];

  if (tid < 256) sh_h2[tid] = ((const u32*)(Xc + (size_t)b*XROW + 512))[tid];
  __syncthreads();

  // proj[n=tid]: 64 iterations of u32x4 (4 k-pairs). Wave load = 1KB contiguous.
  {
    const u32* wp = WhQ + ((size_t)tid << 2);
    const u32x4* hp = (const u32x4*)sh_h2;
    float a0=0.f, a1=0.f, a2=0.f, a3=0.f;
#pragma unroll 8
    for (int kq=0; kq<64; kq++){
      u32x4 wq = *(const u32x4*)(wp + ((size_t)kq << 11));
      u32x4 hq = hp[kq];
      a0 = dot2f(wq.x, hq.x, a0);
      a1 = dot2f(wq.y, hq.y, a1);
      a2 = dot2f(wq.z, hq.z, a2);
      a3 = dot2f(wq.w, hq.w, a3);
    }
    sh_proj[tid] = (a0+a1) + (a2+a3) + bh2h[tid];
  }
  __syncthreads();

  // logit: 8 waves x 12 rows; lane owns 8 H-cols (coalesced 1KB row reads).
  {
    float pv[8], wv[8];
#pragma unroll
    for (int j=0;j<8;j++){ pv[j]=sh_proj[lane*8+j]; wv[j]=wsc[lane*8+j]; }
    const int l0 = q*96 + wid*12;
    const f16* sp0 = (const f16*)sf + (((size_t)(b*L_ + l0)) << 9) + lane*8;
#pragma unroll 4
    for (int i=0;i<12;i++){
      f16x8 s = *(const f16x8*)(sp0 + ((size_t)i << 9));
      float v;
      v  = tanh_f((float)s[0]+pv[0])*wv[0];
      v += tanh_f((float)s[1]+pv[1])*wv[1];
      v += tanh_f((float)s[2]+pv[2])*wv[2];
      v += tanh_f((float)s[3]+pv[3])*wv[3];
      v += tanh_f((float)s[4]+pv[4])*wv[4];
      v += tanh_f((float)s[5]+pv[5])*wv[5];
      v += tanh_f((float)s[6]+pv[6])*wv[6];
      v += tanh_f((float)s[7]+pv[7])*wv[7];
      v = wredsum(v);
      if (lane == 0) logit[b*L_ + l0 + i] = v;
    }
  }
}

// ---------------- step kernel B: softmax + context (row-major coalesced).
// grid 64 (one per batch) x 512 threads.
__global__ __launch_bounds__(512) void k_ctx2(
    const float* __restrict__ logit, const f16* __restrict__ src16,
    f16* __restrict__ Xc)
{
  const int b   = blockIdx.x;
  const int tid = threadIdx.x;
  const int wid = tid >> 6, lane = tid & 63;

  __shared__ float sh_al[L_];
  __shared__ float sh_red[16];
  __shared__ float sh_cp[8][512];

  // softmax over 384 (verified round-2 pattern)
  float inv;
  {
    float va = (tid < L_) ? logit[b*L_ + tid] : -3.0e38f;
    float m = va;
#pragma unroll
    for (int o=32;o>0;o>>=1) m = fmaxf(m, __shfl_down(m,o,64));
    if (lane==0) sh_red[wid] = m;
    __syncthreads();
    m = fmaxf(fmaxf(fmaxf(sh_red[0],sh_red[1]),fmaxf(sh_red[2],sh_red[3])),
              fmaxf(fmaxf(sh_red[4],sh_red[5]),fmaxf(sh_red[6],sh_red[7])));
    float e = (tid < L_) ? __expf(va - m) : 0.f;
    if (tid < L_) sh_al[tid] = e;
    float ss = wredsum(e);
    if (lane==0) sh_red[8+wid] = ss;
    __syncthreads();
    inv = 1.f/(((sh_red[8]+sh_red[9])+(sh_red[10]+sh_red[11]))
             + ((sh_red[12]+sh_red[13])+(sh_red[14]+sh_red[15])));
  }

  // ctx: wave w streams rows l = 48w..48w+47 (1KB contiguous per row);
  // lane accumulates 8 columns (lane*8 .. +8).
  {
    float acc[8] = {0.f,0.f,0.f,0.f,0.f,0.f,0.f,0.f};
    const f16* sp0 = src16 + (((size_t)(b*L_ + wid*48)) << 9) + lane*8;
    const float* alp = sh_al + wid*48;
#pragma unroll 4
    for (int i=0;i<48;i++){
      f16x8 v = *(const f16x8*)(sp0 + ((size_t)i << 9));
      float al = alp[i];
#pragma unroll
      for (int e=0;e<8;e++) acc[e] += al*(float)v[e];
    }
#pragma unroll
    for (int e=0;e<8;e++) sh_cp[wid][lane*8+e] = acc[e];
  }
  __syncthreads();
  if (tid < 256){
    int c0 = tid*2;
    float v0 = (((sh_cp[0][c0]+sh_cp[1][c0])+(sh_cp[2][c0]+sh_cp[3][c0]))
              + ((sh_cp[4][c0]+sh_cp[5][c0])+(sh_cp[6][c0]+sh_cp[7][c0])))*inv;
    int c1 = c0+1;
    float v1 = (((sh_cp[0][c1]+sh_cp[1][c1])+(sh_cp[2][c1]+sh_cp[3][c1]))
              + ((sh_cp[4][c1]+sh_cp[5][c1])+(sh_cp[6][c1]+sh_cp[7][c1])))*inv;
    u32 o = (u32)f2h(v0) | ((u32)f2h(v1) << 16);
    ((u32*)(Xc + (size_t)b*XROW))[tid] = o;
  }
}

// ---------------- step kernel C: gates MFMA + LSTM cell (verified round 2).
// grid 128 x 256 thr; block j owns h-dims [4j,4j+4) x 4 gates (16 packed Wg rows).
__global__ __launch_bounds__(256) void k_gates(
    const f16* __restrict__ X, const f16* __restrict__ Wg,
    const float* __restrict__ bias_g, const f16* __restrict__ embseq,
    float* __restrict__ cbuf, f16* __restrict__ Xn, u16* __restrict__ hs, int t)
{
  __shared__ float gbuf[64][17];
  const int tid  = threadIdx.x;
  const int wid  = tid >> 6, lane = tid & 63;
  const int quad = lane >> 4, l16 = lane & 15;
  const int j = blockIdx.x;
  const f16* bp   = Wg + (size_t)(j*16 + l16)*1280 + quad*8;
  const int brow  = wid*16 + l16;
  const f16* actx = X + (size_t)brow*XROW + quad*8;
  const f16* aemb = embseq + (((size_t)brow*T_ + t)<<8) + quad*8;
  const f16* ah   = actx + 512;
  f32x4 acc = {};
#pragma unroll
  for (int k0=0;k0<512;k0+=32)
    acc = __builtin_amdgcn_mfma_f32_16x16x32_f16(*(const f16x8*)(actx+k0), *(const f16x8*)(bp+k0), acc, 0,0,0);
#pragma unroll
  for (int k0=0;k0<256;k0+=32)
    acc = __builtin_amdgcn_mfma_f32_16x16x32_f16(*(const f16x8*)(aemb+k0), *(const f16x8*)(bp+512+k0), acc, 0,0,0);
#pragma unroll
  for (int k0=0;k0<512;k0+=32)
    acc = __builtin_amdgcn_mfma_f32_16x16x32_f16(*(const f16x8*)(ah+k0), *(const f16x8*)(bp+768+k0), acc, 0,0,0);
#pragma unroll
  for (int r=0;r<4;r++) gbuf[wid*16 + quad*4 + r][l16] = acc[r];
  __syncthreads();
  const int b = tid >> 2, hl = tid & 3;
  const int hd = j*4 + hl;
  float gi = gbuf[b][ 0+hl] + bias_g[j*16 +  0 + hl];
  float gf = gbuf[b][ 4+hl] + bias_g[j*16 +  4 + hl];
  float gg = gbuf[b][ 8+hl] + bias_g[j*16 +  8 + hl];
  float go = gbuf[b][12+hl] + bias_g[j*16 + 12 + hl];
  float fi=sigm_f(gi), ff=sigm_f(gf), fg=tanh_f(gg), fo=sigm_f(go);
  size_t ci = ((size_t)b<<9) + hd;
  float cn = ff*cbuf[ci] + fi*fg;
  float hn = fo*tanh_f(cn);
  cbuf[ci] = cn;
  Xn[(size_t)b*XROW + 512 + hd] = (f16)hn;
  hs[(((size_t)(b*T_ + t))<<9) + hd] = f2h(hn);
}

extern "C" void kernel_launch(void* const* d_in, const int* in_sizes, int n_in,
                              void* d_out, int out_size, void* d_ws, size_t ws_size,
                              hipStream_t stream)
{
  const float* src   = (const float*)d_in[0];
  const int*   text  = (const int*)d_in[1];
  const float* embt  = (const float*)d_in[2];
  const float* Wi2h  = (const float*)d_in[3];
  const float* Wh2h  = (const float*)d_in[4];
  const float* bh2h  = (const float*)d_in[5];
  const float* wsc   = (const float*)d_in[6];
  const float* W_ih  = (const float*)d_in[7];
  const float* b_ih  = (const float*)d_in[8];
  const float* W_hh  = (const float*)d_in[9];
  const float* b_hh  = (const float*)d_in[10];
  const float* Wgen  = (const float*)d_in[11];
  const float* bgen  = (const float*)d_in[12];
  float* out = (float*)d_out;

  // Workspace (~70 MB)
  char* p = (char*)d_ws;
  u16*   sfw    = (u16*)p;    p += (size_t)B_*L_*H_*2;        // 25.2 MB
  u16*   hsw    = (u16*)p;    p += (size_t)B_*T_*H_*2;        //  8.3 MB
  f16*   src16  = (f16*)p;    p += (size_t)B_*L_*CS*2;        // 25.2 MB
  u32*   WhQ    = (u32*)p;    p += (size_t)64*512*4*4;        //  0.5 MB
  f16*   Wi2h16 = (f16*)p;    p += (size_t)H_*CS*2;           //  0.5 MB
  f16*   WgF    = (f16*)p;    p += (size_t)2048*1280*2;       //  5.2 MB
  f16*   embseq = (f16*)p;    p += (size_t)B_*T_*E_*2;        //  4.2 MB
  f16*   X0     = (f16*)p;    p += (size_t)B_*XROW*2;         //  128 KB
  f16*   X1     = (f16*)p;    p += (size_t)B_*XROW*2;         //  128 KB
  float* logitw = (float*)p;  p += (size_t)B_*L_*4;           //   98 KB
  float* cbuf   = (float*)p;  p += (size_t)B_*H_*4;           //  128 KB
  float* bias_g = (float*)p;  p += (size_t)2048*4;            //    8 KB

  hipMemsetAsync(X0,   0, (size_t)B_*XROW*2*2, stream);   // X0+X1 contiguous
  hipMemsetAsync(cbuf, 0, (size_t)B_*H_*4, stream);

  // one-time conversions / packing
  k_cvt    <<<(H_*CS+255)/256,    256, 0, stream>>>(Wi2h, Wi2h16, H_*CS);
  k_cvt    <<<(B_*L_*CS+255)/256, 256, 0, stream>>>(src, src16, B_*L_*CS);
  k_packwhq<<<(64*512*4+255)/256, 256, 0, stream>>>(Wh2h, WhQ);
  k_packwg <<<(2048*1280+255)/256,256, 0, stream>>>(W_ih, W_hh, b_ih, b_hh, WgF, bias_g);
  k_emb    <<<(B_*T_*E_+255)/256, 256, 0, stream>>>(text, embt, embseq);

  // sf = src @ Wi2h^T  (MFMA f16)
  k_sf_mfma<<<dim3(384,2), 256, 0, stream>>>(src, Wi2h16, sfw);

  // decode loop: 3 kernels per step, all coalesced
  for (int t=0; t<T_; t++){
    f16* Xc = (t & 1) ? X1 : X0;
    f16* Xn = (t & 1) ? X0 : X1;
    k_att1<<<256, 512, 0, stream>>>(WhQ, sfw, Xc, bh2h, wsc, logitw);
    k_ctx2<<<64, 512, 0, stream>>>(logitw, src16, Xc);
    k_gates<<<128, 256, 0, stream>>>(Xc, WgF, bias_g, embseq, cbuf, Xn, hsw, t);
  }

  // probs = hs @ Wgen^T + bgen
  dim3 g2(B_*T_/64, (NC+63)/64);
  gemm_probs<<<g2, 256, 0, stream>>>(hsw, Wgen, bgen, out, B_*T_, NC, H_);
}